// Round 8
// baseline (3465.522 us; speedup 1.0000x reference)
//
#include <hip/hip_runtime.h>

// Problem constants
#define BB 4
#define SS 32
#define CC 128
#define HH 16
#define WW 32
#define HID 128
#define DEPTH 2
#define CIN 256           // CC + HID
#define COUT 512          // 4*HID
#define K9 (CIN * 9)      // 2304
#define KH 1152           // tap-major: k = tap*128 + ch
#define HW (HH * WW)      // 512
#define MM (BB * HW)      // 2048
#define MBIG (SS * BB * HW) // 65536

typedef __attribute__((ext_vector_type(4))) float f32x4;
typedef __attribute__((ext_vector_type(8))) short bf16x8;

static __device__ __forceinline__ unsigned short f2bf(float f) {
    union { float f; unsigned u; } v; v.f = f;
    unsigned r = v.u + 0x7FFF + ((v.u >> 16) & 1);   // RNE
    return (unsigned short)(r >> 16);
}
static __device__ __forceinline__ float bf2f(unsigned short h) {
    union { float f; unsigned u; } v; v.u = ((unsigned)h) << 16; return v.f;
}
static __device__ __forceinline__ unsigned packhl(float f) {
    unsigned short hi = f2bf(f);
    unsigned short lo = f2bf(f - bf2f(hi));
    return (unsigned)hi | ((unsigned)lo << 16);
}

// ---------------------------------------------------------------------------
// Weight split+transpose (tap-major k), packed bf16 hi|lo:
//   wtx_hl [DEPTH][KH][COUT]  x-part, n unchanged
//   wth_hl [DEPTH][KH][COUT]  h-part, n GATE-GATHERED: n' = hb*64 + g*16 + j
//     (orig n = g*128 + hb*16 + j)  -> one 64-wide n-tile = all 4 gates
//     for a 16-hid slice.
// ---------------------------------------------------------------------------
__global__ void transpose_w_kernel(const float* __restrict__ w,
                                   unsigned* __restrict__ wtx_hl,
                                   unsigned* __restrict__ wth_hl) {
    int idx = blockIdx.x * 256 + threadIdx.x;
    if (idx >= DEPTH * K9 * COUT) return;
    int n = idx % COUT;
    int k = (idx / COUT) % K9;
    int d = idx / (COUT * K9);
    int cin = k / 9, tap = k % 9;
    float v = w[(((long)(d * COUT + n) * CIN + cin) * 9) + tap];
    unsigned p = packhl(v);
    if (cin < CC) {
        wtx_hl[((long)d * KH + (tap * CC + cin)) * COUT + n] = p;
    } else {
        int ch = cin - CC;
        int g = n >> 7, r = n & 127;
        int ng = (r >> 4) * 64 + g * 16 + (r & 15);
        wth_hl[((long)d * KH + (tap * HID + ch)) * COUT + ng] = p;
    }
}

// ---------------------------------------------------------------------------
// Broadcast init_h/init_c[d] into packed-h / fp32-c state buffers
// ---------------------------------------------------------------------------
__global__ void init_state_kernel(const float* __restrict__ ih, const float* __restrict__ ic,
                                  unsigned* __restrict__ hhl, float* __restrict__ c, int d) {
    int idx = blockIdx.x * 256 + threadIdx.x;   // B*HID*HW = 262144
    int hid = (idx >> 9) & (HID - 1);
    hhl[idx] = packhl(ih[d * HID + hid]);
    c[idx] = ic[d * HID + hid];
}

// ---------------------------------------------------------------------------
// Big feed-forward GEMM over ALL timesteps — MFMA bf16x3 (hi/lo split).
// Tile 128x128, 4 waves (2x2 of 64x64), BK=32 tap-major.
// HL=0: fp32 input (layer 1); HL=1: packed hi|lo input. grid = (512, 4).
// ---------------------------------------------------------------------------
template<int HL>
__launch_bounds__(256)
__global__ void big_gemm_mfma(const void* __restrict__ xin_, long strideS, long strideB,
                              const unsigned* __restrict__ wt_hl,  // [KH][COUT]
                              float* __restrict__ zx) {
    __shared__ unsigned short Ah[128][36], Al[128][36];
    __shared__ unsigned short Bh[128][36], Bl[128][36];

    const int m0 = blockIdx.x * 128;
    const int n0 = blockIdx.y * 128;
    const int tid  = threadIdx.x;
    const int lane = tid & 63;
    const int wid  = tid >> 6;          // 4 waves
    const int wm = (wid >> 1) * 64;
    const int wn = (wid & 1) * 64;
    const int sb  = m0 >> 9;            // image index
    const int hw0 = m0 & 511;
    const long imgoff = (long)(sb >> 2) * strideS + (long)(sb & 3) * strideB;
    const float*    imgf = (const float*)xin_ + imgoff;
    const unsigned* imgu = (const unsigned*)xin_ + imgoff;

    f32x4 acc[4][4];
    #pragma unroll
    for (int i = 0; i < 4; ++i)
        #pragma unroll
        for (int j = 0; j < 4; ++j)
            acc[i][j] = (f32x4){0.f, 0.f, 0.f, 0.f};

    for (int k0 = 0; k0 < KH; k0 += 32) {
        const int tap = k0 >> 7;
        const int c0  = k0 & 127;
        const int ky  = tap / 3 - 1;
        const int kx  = tap - (tap / 3) * 3 - 1;
        #pragma unroll
        for (int i = 0; i < 16; ++i) {
            int idx = i * 256 + tid;
            int kk = idx >> 7;
            int m  = idx & 127;
            int hw = hw0 + m;
            int yy = (hw >> 5) + ky;
            int xq = (hw & 31) + kx;
            bool ok = (unsigned)yy < (unsigned)HH && (unsigned)xq < (unsigned)WW;
            if constexpr (HL) {
                unsigned p = ok ? imgu[(c0 + kk) * HW + yy * WW + xq] : 0u;
                Ah[m][kk] = (unsigned short)p;
                Al[m][kk] = (unsigned short)(p >> 16);
            } else {
                float v = ok ? imgf[(c0 + kk) * HW + yy * WW + xq] : 0.f;
                unsigned short h = f2bf(v);
                Ah[m][kk] = h;
                Al[m][kk] = f2bf(v - bf2f(h));
            }
        }
        #pragma unroll
        for (int i = 0; i < 16; ++i) {
            int idx = i * 256 + tid;
            int kk = idx >> 7;
            int n  = idx & 127;
            unsigned p = wt_hl[(long)(k0 + kk) * COUT + n0 + n];
            Bh[n][kk] = (unsigned short)p;
            Bl[n][kk] = (unsigned short)(p >> 16);
        }
        __syncthreads();

        const int fr = lane & 15;
        const int kq = (lane >> 4) * 8;
        bf16x8 ah[4], al[4], bh[4], bl[4];
        #pragma unroll
        for (int f = 0; f < 4; ++f) {
            ah[f] = *(const bf16x8*)&Ah[wm + f * 16 + fr][kq];
            al[f] = *(const bf16x8*)&Al[wm + f * 16 + fr][kq];
            bh[f] = *(const bf16x8*)&Bh[wn + f * 16 + fr][kq];
            bl[f] = *(const bf16x8*)&Bl[wn + f * 16 + fr][kq];
        }
        #pragma unroll
        for (int fm = 0; fm < 4; ++fm)
            #pragma unroll
            for (int fn = 0; fn < 4; ++fn) {
                acc[fm][fn] = __builtin_amdgcn_mfma_f32_16x16x32_bf16(ah[fm], bh[fn], acc[fm][fn], 0, 0, 0);
                acc[fm][fn] = __builtin_amdgcn_mfma_f32_16x16x32_bf16(ah[fm], bl[fn], acc[fm][fn], 0, 0, 0);
                acc[fm][fn] = __builtin_amdgcn_mfma_f32_16x16x32_bf16(al[fm], bh[fn], acc[fm][fn], 0, 0, 0);
            }
        __syncthreads();
    }

    const long outbase = (long)sb * COUT * HW;
    const int rm = (lane >> 4) * 4;
    const int cn = lane & 15;
    #pragma unroll
    for (int fm = 0; fm < 4; ++fm)
        #pragma unroll
        for (int fn = 0; fn < 4; ++fn) {
            int m = hw0 + wm + fm * 16 + rm;
            int n = n0 + wn + fn * 16 + cn;
            *(float4*)&zx[outbase + (long)n * HW + m] = *(float4*)&acc[fm][fn];
        }
}

// ---------------------------------------------------------------------------
// FUSED per-step kernel: recurrent GEMM (full K=1152, MFMA bf16x3) + split-K-
// free epilogue doing the entire LSTM cell update.
// n-tile (64) = 4 gates x 16 hid (gate-gathered weights) -> the cell update
// for (m-tile, hid-slice) is wg-local. Reads h_{t-1} from hin, writes packed
// h_t to hout (different buffers -> no cross-wg race). c is RMW'd by its
// owning wg only. grid = (32, 8), 256 threads, 4 waves (2x2 of 32x32).
// ---------------------------------------------------------------------------
__launch_bounds__(256)
__global__ void step_fused(const unsigned* __restrict__ hin,     // [B][HID][HW] packed h_{t-1}
                           const unsigned* __restrict__ wth_g,   // [KH][COUT] gate-gathered
                           const float* __restrict__ zx_s,       // [B][COUT][HW] step slice
                           const float* __restrict__ bias,       // [COUT] original order
                           float* __restrict__ c,                // [B][HID][HW] fp32 state
                           unsigned* __restrict__ hout) {        // [B][HID][HW] packed h_t
    __shared__ __align__(16) union {
        struct { unsigned short Ah[64][36], Al[64][36], Bh[64][36], Bl[64][36]; } s;
        float zt[64][68];   // [n][m]
    } u;

    const int m0   = blockIdx.x * 64;
    const int n0g  = blockIdx.y * 64;       // gathered-n base
    const int hid0 = blockIdx.y * 16;
    const int tid  = threadIdx.x;
    const int lane = tid & 63;
    const int wid  = tid >> 6;
    const int wm = (wid >> 1) * 32;
    const int wn = (wid & 1) * 32;
    const int b   = m0 >> 9;
    const int hw0 = m0 & 511;

    f32x4 acc[2][2];
    #pragma unroll
    for (int i = 0; i < 2; ++i)
        #pragma unroll
        for (int j = 0; j < 2; ++j)
            acc[i][j] = (f32x4){0.f, 0.f, 0.f, 0.f};

    unsigned pa[8], pb[8];
    auto loadA = [&](int t) {
        const int k0  = t * 32;
        const int tap = k0 >> 7;
        const int c0  = k0 & 127;
        const int ky  = tap / 3 - 1;
        const int kx  = tap - (tap / 3) * 3 - 1;
        #pragma unroll
        for (int i = 0; i < 8; ++i) {
            int idx = i * 256 + tid;
            int kk = idx >> 6;
            int m  = idx & 63;
            int hw = hw0 + m;
            int yy = (hw >> 5) + ky;
            int xq = (hw & 31) + kx;
            bool ok = (unsigned)yy < (unsigned)HH && (unsigned)xq < (unsigned)WW;
            pa[i] = ok ? hin[((long)(b * HID + c0 + kk)) * HW + yy * WW + xq] : 0u;
        }
    };
    auto loadB = [&](int t) {
        #pragma unroll
        for (int i = 0; i < 8; ++i) {
            int idx = i * 256 + tid;
            int kk = idx >> 6;
            int n  = idx & 63;
            pb[i] = wth_g[(long)(t * 32 + kk) * COUT + n0g + n];
        }
    };
    auto commit = [&]() {
        #pragma unroll
        for (int i = 0; i < 8; ++i) {
            int idx = i * 256 + tid;
            int kk = idx >> 6;
            int mn = idx & 63;
            u.s.Ah[mn][kk] = (unsigned short)pa[i];
            u.s.Al[mn][kk] = (unsigned short)(pa[i] >> 16);
            u.s.Bh[mn][kk] = (unsigned short)pb[i];
            u.s.Bl[mn][kk] = (unsigned short)(pb[i] >> 16);
        }
    };

    loadA(0); loadB(0);
    commit();
    __syncthreads();

    for (int t = 0; t < KH / 32; ++t) {
        const bool more = (t + 1 < KH / 32);
        if (more) { loadA(t + 1); loadB(t + 1); }

        const int fr = lane & 15;
        const int kq = (lane >> 4) * 8;
        bf16x8 ah[2], al[2], bh[2], bl[2];
        #pragma unroll
        for (int f = 0; f < 2; ++f) {
            ah[f] = *(const bf16x8*)&u.s.Ah[wm + f * 16 + fr][kq];
            al[f] = *(const bf16x8*)&u.s.Al[wm + f * 16 + fr][kq];
            bh[f] = *(const bf16x8*)&u.s.Bh[wn + f * 16 + fr][kq];
            bl[f] = *(const bf16x8*)&u.s.Bl[wn + f * 16 + fr][kq];
        }
        #pragma unroll
        for (int fm = 0; fm < 2; ++fm)
            #pragma unroll
            for (int fn = 0; fn < 2; ++fn) {
                acc[fm][fn] = __builtin_amdgcn_mfma_f32_16x16x32_bf16(ah[fm], bh[fn], acc[fm][fn], 0, 0, 0);
                acc[fm][fn] = __builtin_amdgcn_mfma_f32_16x16x32_bf16(ah[fm], bl[fn], acc[fm][fn], 0, 0, 0);
                acc[fm][fn] = __builtin_amdgcn_mfma_f32_16x16x32_bf16(al[fm], bh[fn], acc[fm][fn], 0, 0, 0);
            }
        __syncthreads();
        if (more) {
            commit();
            __syncthreads();
        }
    }

    // --- spill z-tile to LDS (union member switch: all prior reads synced) ---
    {
        const int rm = (lane >> 4) * 4;
        const int cn = lane & 15;
        #pragma unroll
        for (int fm = 0; fm < 2; ++fm)
            #pragma unroll
            for (int fn = 0; fn < 2; ++fn) {
                int m = wm + fm * 16 + rm;
                int n = wn + fn * 16 + cn;
                *(float4*)&u.zt[n][m] = *(float4*)&acc[fm][fn];
            }
    }
    __syncthreads();

    // --- gate math: 1024 cell elements (64 m x 16 hid), 4 per thread ---
    #pragma unroll
    for (int i = 0; i < 4; ++i) {
        int e = i * 256 + tid;
        int m = e & 63;
        int j = e >> 6;             // hid slice index 0..15
        float g[4];
        #pragma unroll
        for (int gi = 0; gi < 4; ++gi) {
            int n_orig = gi * 128 + hid0 + j;
            g[gi] = u.zt[gi * 16 + j][m]
                  + zx_s[((long)b * COUT + n_orig) * HW + hw0 + m]
                  + bias[n_orig];
        }
        long idx_s = ((long)(b * HID + hid0 + j)) * HW + hw0 + m;
        float si = 1.f / (1.f + expf(-g[0]));
        float sf = 1.f / (1.f + expf(-g[1]));
        float so = 1.f / (1.f + expf(-g[3]));
        float cs = sf * c[idx_s] + si * tanhf(g[2]);
        float hs = so * tanhf(cs);
        c[idx_s] = cs;
        hout[idx_s] = packhl(hs);
    }
}

// ---------------------------------------------------------------------------
// Mean pool over HW: seq_hl [S][B][HID][HW] packed -> pooled [S*B*HID]
// ---------------------------------------------------------------------------
__global__ void pool_kernel(const unsigned* __restrict__ seq_hl, float* __restrict__ pooled) {
    int row  = blockIdx.x * 4 + (threadIdx.x >> 6);
    int lane = threadIdx.x & 63;
    const unsigned* p = seq_hl + (long)row * HW;
    float sum = 0.f;
    #pragma unroll
    for (int i = 0; i < HW / 64; ++i) {
        unsigned u = p[lane + i * 64];
        sum += bf2f((unsigned short)u) + bf2f((unsigned short)(u >> 16));
    }
    #pragma unroll
    for (int off = 32; off; off >>= 1) sum += __shfl_down(sum, off);
    if (lane == 0) pooled[row] = sum * (1.f / HW);
}

// ---------------------------------------------------------------------------
// FC + ReLU + two scalar heads.
// ---------------------------------------------------------------------------
__global__ void head_kernel(const float* __restrict__ pooled,
                            const float* __restrict__ fc_w, const float* __restrict__ fc_b,
                            const float* __restrict__ fco_w, const float* __restrict__ fco_b,
                            const float* __restrict__ fca_w, const float* __restrict__ fca_b,
                            float* __restrict__ out) {
    int bs = blockIdx.x;          // b*S + s
    int b  = bs / SS;
    int s  = bs % SS;
    int j  = threadIdx.x;
    const float* prow = pooled + (long)(s * BB + b) * HID;
    float acc = fc_b[j];
    #pragma unroll 4
    for (int k = 0; k < HID; ++k) acc += fc_w[j * HID + k] * prow[k];
    float f = fmaxf(acc, 0.f);
    __shared__ float ro[128], ra[128];
    ro[j] = f * fco_w[j];
    ra[j] = f * fca_w[j];
    __syncthreads();
    for (int off = 64; off; off >>= 1) {
        if (j < off) { ro[j] += ro[j + off]; ra[j] += ra[j + off]; }
        __syncthreads();
    }
    if (j == 0) {
        out[bs]           = ro[0] + fco_b[0];
        out[BB * SS + bs] = ra[0] + fca_b[0];
    }
}

// ---------------------------------------------------------------------------
extern "C" void kernel_launch(void* const* d_in, const int* in_sizes, int n_in,
                              void* d_out, int out_size, void* d_ws, size_t ws_size,
                              hipStream_t stream) {
    const float* x      = (const float*)d_in[0];
    const float* conv_w = (const float*)d_in[1];
    const float* conv_b = (const float*)d_in[2];
    const float* init_h = (const float*)d_in[3];
    const float* init_c = (const float*)d_in[4];
    const float* fc_w   = (const float*)d_in[5];
    const float* fc_b   = (const float*)d_in[6];
    const float* fco_w  = (const float*)d_in[7];
    const float* fco_b  = (const float*)d_in[8];
    const float* fca_w  = (const float*)d_in[9];
    const float* fca_b  = (const float*)d_in[10];
    float* out = (float*)d_out;

    // Workspace carve-up (4B units), total ~44.8M words = ~179 MB.
    unsigned* wtx_hl = (unsigned*)d_ws;                    // DEPTH*KH*COUT = 1,179,648
    unsigned* wth_hl = wtx_hl + (long)DEPTH * KH * COUT;   // 1,179,648
    float* zx        = (float*)(wth_hl + (long)DEPTH * KH * COUT); // S*B*COUT*HW = 33,554,432
    unsigned* seq_hl = (unsigned*)(zx + (long)SS * BB * COUT * HW); // S*B*HID*HW = 8,388,608
    unsigned* hhl    = seq_hl + (long)SS * BB * HID * HW;           // 262,144
    float* cbuf      = (float*)(hhl + (long)BB * HID * HW);         // 262,144
    float* pooled    = cbuf + (long)BB * HID * HW;                  // 16,384

    transpose_w_kernel<<<(DEPTH * K9 * COUT + 255) / 256, 256, 0, stream>>>(conv_w, wtx_hl, wth_hl);

    const long ZSTEP = (long)BB * COUT * HW;
    const long QSTEP = (long)BB * HID * HW;

    for (int d = 0; d < DEPTH; ++d) {
        // x-part of the conv for ALL timesteps: one big parallel MFMA GEMM
        if (d == 0)
            big_gemm_mfma<0><<<dim3(MBIG / 128, COUT / 128), 256, 0, stream>>>(
                x, (long)CC * HW, (long)SS * CC * HW, wtx_hl, zx);
        else
            big_gemm_mfma<1><<<dim3(MBIG / 128, COUT / 128), 256, 0, stream>>>(
                seq_hl, (long)BB * HID * HW, (long)HID * HW, wtx_hl + (long)KH * COUT, zx);

        init_state_kernel<<<(BB * HID * HW) / 256, 256, 0, stream>>>(init_h, init_c, hhl, cbuf, d);

        const unsigned* wth_d = wth_hl + (long)d * KH * COUT;
        const float* bias_d   = conv_b + d * COUT;
        for (int s = 0; s < SS; ++s) {
            const unsigned* hin = (s == 0) ? hhl : seq_hl + (long)(s - 1) * QSTEP;
            step_fused<<<dim3(MM / 64, HID / 16), 256, 0, stream>>>(
                hin, wth_d, zx + (long)s * ZSTEP, bias_d, cbuf, seq_hl + (long)s * QSTEP);
        }
    }
    pool_kernel<<<(SS * BB * HID) / 4, 256, 0, stream>>>(seq_hl, pooled);
    head_kernel<<<BB * SS, 128, 0, stream>>>(pooled, fc_w, fc_b, fco_w, fco_b, fca_w, fca_b, out);
}

// Round 9
// 2995.689 us; speedup vs baseline: 1.1568x; 1.1568x over previous
//
#include <hip/hip_runtime.h>

// Problem constants
#define BB 4
#define SS 32
#define CC 128
#define HH 16
#define WW 32
#define HID 128
#define DEPTH 2
#define CIN 256           // CC + HID
#define COUT 512          // 4*HID
#define K9 (CIN * 9)      // 2304
#define KH 1152           // tap-major: k = tap*128 + ch
#define HW (HH * WW)      // 512
#define MM (BB * HW)      // 2048
#define MBIG (SS * BB * HW) // 65536

typedef __attribute__((ext_vector_type(4))) float f32x4;
typedef __attribute__((ext_vector_type(8))) short bf16x8;

static __device__ __forceinline__ unsigned short f2bf(float f) {
    union { float f; unsigned u; } v; v.f = f;
    unsigned r = v.u + 0x7FFF + ((v.u >> 16) & 1);   // RNE
    return (unsigned short)(r >> 16);
}
static __device__ __forceinline__ float bf2f(unsigned short h) {
    union { float f; unsigned u; } v; v.u = ((unsigned)h) << 16; return v.f;
}
static __device__ __forceinline__ unsigned packhl(float f) {
    unsigned short hi = f2bf(f);
    unsigned short lo = f2bf(f - bf2f(hi));
    return (unsigned)hi | ((unsigned)lo << 16);
}

// ---------------------------------------------------------------------------
// Weight split+transpose (tap-major k), packed bf16 hi|lo:
//   wtx_hl [DEPTH][KH][COUT]  x-part, n unchanged
//   wth_hl [DEPTH][KH][COUT]  h-part, n GATE-GATHERED: n' = hb*64 + g*16 + j
// ---------------------------------------------------------------------------
__global__ void transpose_w_kernel(const float* __restrict__ w,
                                   unsigned* __restrict__ wtx_hl,
                                   unsigned* __restrict__ wth_hl) {
    int idx = blockIdx.x * 256 + threadIdx.x;
    if (idx >= DEPTH * K9 * COUT) return;
    int n = idx % COUT;
    int k = (idx / COUT) % K9;
    int d = idx / (COUT * K9);
    int cin = k / 9, tap = k % 9;
    float v = w[(((long)(d * COUT + n) * CIN + cin) * 9) + tap];
    unsigned p = packhl(v);
    if (cin < CC) {
        wtx_hl[((long)d * KH + (tap * CC + cin)) * COUT + n] = p;
    } else {
        int ch = cin - CC;
        int g = n >> 7, r = n & 127;
        int ng = (r >> 4) * 64 + g * 16 + (r & 15);
        wth_hl[((long)d * KH + (tap * HID + ch)) * COUT + ng] = p;
    }
}

// ---------------------------------------------------------------------------
// Broadcast init_h/init_c[d] into packed-h / fp32-c state buffers
// ---------------------------------------------------------------------------
__global__ void init_state_kernel(const float* __restrict__ ih, const float* __restrict__ ic,
                                  unsigned* __restrict__ hhl, float* __restrict__ c, int d) {
    int idx = blockIdx.x * 256 + threadIdx.x;   // B*HID*HW = 262144
    int hid = (idx >> 9) & (HID - 1);
    hhl[idx] = packhl(ih[d * HID + hid]);
    c[idx] = ic[d * HID + hid];
}

// ---------------------------------------------------------------------------
// Big feed-forward GEMM over ALL timesteps — MFMA bf16x3 (hi/lo split).
// Tile 128x128, 4 waves (2x2 of 64x64), BK=64 (two 32-k subtiles), tap-major.
// Register-prefetch double buffering: next tile's global loads issue before
// the current tile's MFMA loop. Paired b32 LDS commits.
// HL=0: fp32 input (layer 1); HL=1: packed hi|lo input. grid = (512, 4).
// ---------------------------------------------------------------------------
template<int HL>
__launch_bounds__(256)
__global__ void big_gemm_mfma(const void* __restrict__ xin_, long strideS, long strideB,
                              const unsigned* __restrict__ wt_hl,  // [KH][COUT]
                              float* __restrict__ zx) {
    __shared__ unsigned short Ah[2][128][36], Al[2][128][36];   // 18 KB each
    __shared__ unsigned short Bh[2][128][36], Bl[2][128][36];   // total 72 KB

    const int m0 = blockIdx.x * 128;
    const int n0 = blockIdx.y * 128;
    const int tid  = threadIdx.x;
    const int lane = tid & 63;
    const int wid  = tid >> 6;          // 4 waves
    const int wm = (wid >> 1) * 64;
    const int wn = (wid & 1) * 64;
    const int sb  = m0 >> 9;            // image index
    const int hw0 = m0 & 511;
    const long imgoff = (long)(sb >> 2) * strideS + (long)(sb & 3) * strideB;
    const float*    imgf = (const float*)xin_ + imgoff;
    const unsigned* imgu = (const unsigned*)xin_ + imgoff;

    f32x4 acc[4][4];
    #pragma unroll
    for (int i = 0; i < 4; ++i)
        #pragma unroll
        for (int j = 0; j < 4; ++j)
            acc[i][j] = (f32x4){0.f, 0.f, 0.f, 0.f};

    unsigned pa[32], pb[32];            // prefetch: 16 channel-pairs each

    // tile t covers k = t*64 .. t*64+63 (one tap; ch base c0 = (t&1)*64)
    auto loadA = [&](int t) {
        const int k0  = t * 64;
        const int tap = k0 >> 7;
        const int c0  = k0 & 127;
        const int ky  = tap / 3 - 1;
        const int kx  = tap - (tap / 3) * 3 - 1;
        #pragma unroll
        for (int i = 0; i < 16; ++i) {
            int idx = i * 256 + tid;    // 0..4095 : kkp = pair index, m
            int kkp = idx >> 7;         // 0..31
            int m   = idx & 127;
            int hw = hw0 + m;
            int yy = (hw >> 5) + ky;
            int xq = (hw & 31) + kx;
            bool ok = (unsigned)yy < (unsigned)HH && (unsigned)xq < (unsigned)WW;
            int ch = c0 + 2 * kkp;
            if constexpr (HL) {
                pa[2 * i]     = ok ? imgu[ch * HW + yy * WW + xq] : 0u;
                pa[2 * i + 1] = ok ? imgu[(ch + 1) * HW + yy * WW + xq] : 0u;
            } else {
                float v0 = ok ? imgf[ch * HW + yy * WW + xq] : 0.f;
                float v1 = ok ? imgf[(ch + 1) * HW + yy * WW + xq] : 0.f;
                pa[2 * i]     = packhl(v0);
                pa[2 * i + 1] = packhl(v1);
            }
        }
    };
    auto loadB = [&](int t) {
        const int k0 = t * 64;
        #pragma unroll
        for (int i = 0; i < 16; ++i) {
            int idx = i * 256 + tid;
            int kkp = idx >> 7;         // 0..31 (pair along k)
            int n   = idx & 127;
            pb[2 * i]     = wt_hl[(long)(k0 + 2 * kkp) * COUT + n0 + n];
            pb[2 * i + 1] = wt_hl[(long)(k0 + 2 * kkp + 1) * COUT + n0 + n];
        }
    };
    auto commit = [&]() {
        #pragma unroll
        for (int i = 0; i < 16; ++i) {
            int idx = i * 256 + tid;
            int kkp = idx >> 7;
            int mn  = idx & 127;
            int sub = kkp >> 4;
            int kl  = (2 * kkp) & 31;
            unsigned a0 = pa[2 * i], a1 = pa[2 * i + 1];
            *(unsigned*)&Ah[sub][mn][kl] = (a0 & 0xffffu) | (a1 << 16);
            *(unsigned*)&Al[sub][mn][kl] = (a0 >> 16) | (a1 & 0xffff0000u);
            unsigned b0 = pb[2 * i], b1 = pb[2 * i + 1];
            *(unsigned*)&Bh[sub][mn][kl] = (b0 & 0xffffu) | (b1 << 16);
            *(unsigned*)&Bl[sub][mn][kl] = (b0 >> 16) | (b1 & 0xffff0000u);
        }
    };

    loadA(0); loadB(0);
    commit();
    __syncthreads();

    const int fr = lane & 15;
    const int kq = (lane >> 4) * 8;

    for (int t = 0; t < KH / 64; ++t) {
        const bool more = (t + 1 < KH / 64);
        if (more) { loadA(t + 1); loadB(t + 1); }

        #pragma unroll
        for (int sub = 0; sub < 2; ++sub) {
            bf16x8 ah[4], al[4], bh[4], bl[4];
            #pragma unroll
            for (int f = 0; f < 4; ++f) {
                ah[f] = *(const bf16x8*)&Ah[sub][wm + f * 16 + fr][kq];
                al[f] = *(const bf16x8*)&Al[sub][wm + f * 16 + fr][kq];
                bh[f] = *(const bf16x8*)&Bh[sub][wn + f * 16 + fr][kq];
                bl[f] = *(const bf16x8*)&Bl[sub][wn + f * 16 + fr][kq];
            }
            #pragma unroll
            for (int fm = 0; fm < 4; ++fm)
                #pragma unroll
                for (int fn = 0; fn < 4; ++fn) {
                    acc[fm][fn] = __builtin_amdgcn_mfma_f32_16x16x32_bf16(ah[fm], bh[fn], acc[fm][fn], 0, 0, 0);
                    acc[fm][fn] = __builtin_amdgcn_mfma_f32_16x16x32_bf16(ah[fm], bl[fn], acc[fm][fn], 0, 0, 0);
                    acc[fm][fn] = __builtin_amdgcn_mfma_f32_16x16x32_bf16(al[fm], bh[fn], acc[fm][fn], 0, 0, 0);
                }
        }
        __syncthreads();
        if (more) {
            commit();
            __syncthreads();
        }
    }

    const long outbase = (long)sb * COUT * HW;
    const int rm = (lane >> 4) * 4;
    const int cn = lane & 15;
    #pragma unroll
    for (int fm = 0; fm < 4; ++fm)
        #pragma unroll
        for (int fn = 0; fn < 4; ++fn) {
            int m = hw0 + wm + fm * 16 + rm;
            int n = n0 + wn + fn * 16 + cn;
            *(float4*)&zx[outbase + (long)n * HW + m] = *(float4*)&acc[fm][fn];
        }
}

// ---------------------------------------------------------------------------
// FUSED per-step kernel: recurrent GEMM (full K=1152, MFMA bf16x3) + LSTM
// cell update epilogue (gate-gathered weights make it wg-local).
// grid = (32, 8), 256 threads, 4 waves (2x2 of 32x32).
// ---------------------------------------------------------------------------
__launch_bounds__(256)
__global__ void step_fused(const unsigned* __restrict__ hin,     // [B][HID][HW] packed h_{t-1}
                           const unsigned* __restrict__ wth_g,   // [KH][COUT] gate-gathered
                           const float* __restrict__ zx_s,       // [B][COUT][HW] step slice
                           const float* __restrict__ bias,       // [COUT] original order
                           float* __restrict__ c,                // [B][HID][HW] fp32 state
                           unsigned* __restrict__ hout) {        // [B][HID][HW] packed h_t
    __shared__ __align__(16) union {
        struct { unsigned short Ah[64][36], Al[64][36], Bh[64][36], Bl[64][36]; } s;
        float zt[64][68];   // [n][m]
    } u;

    const int m0   = blockIdx.x * 64;
    const int n0g  = blockIdx.y * 64;       // gathered-n base
    const int hid0 = blockIdx.y * 16;
    const int tid  = threadIdx.x;
    const int lane = tid & 63;
    const int wid  = tid >> 6;
    const int wm = (wid >> 1) * 32;
    const int wn = (wid & 1) * 32;
    const int b   = m0 >> 9;
    const int hw0 = m0 & 511;

    f32x4 acc[2][2];
    #pragma unroll
    for (int i = 0; i < 2; ++i)
        #pragma unroll
        for (int j = 0; j < 2; ++j)
            acc[i][j] = (f32x4){0.f, 0.f, 0.f, 0.f};

    unsigned pa[8], pb[8];
    auto loadA = [&](int t) {
        const int k0  = t * 32;
        const int tap = k0 >> 7;
        const int c0  = k0 & 127;
        const int ky  = tap / 3 - 1;
        const int kx  = tap - (tap / 3) * 3 - 1;
        #pragma unroll
        for (int i = 0; i < 8; ++i) {
            int idx = i * 256 + tid;
            int kk = idx >> 6;
            int m  = idx & 63;
            int hw = hw0 + m;
            int yy = (hw >> 5) + ky;
            int xq = (hw & 31) + kx;
            bool ok = (unsigned)yy < (unsigned)HH && (unsigned)xq < (unsigned)WW;
            pa[i] = ok ? hin[((long)(b * HID + c0 + kk)) * HW + yy * WW + xq] : 0u;
        }
    };
    auto loadB = [&](int t) {
        #pragma unroll
        for (int i = 0; i < 8; ++i) {
            int idx = i * 256 + tid;
            int kk = idx >> 6;
            int n  = idx & 63;
            pb[i] = wth_g[(long)(t * 32 + kk) * COUT + n0g + n];
        }
    };
    auto commit = [&]() {
        #pragma unroll
        for (int i = 0; i < 8; ++i) {
            int idx = i * 256 + tid;
            int kk = idx >> 6;
            int mn = idx & 63;
            u.s.Ah[mn][kk] = (unsigned short)pa[i];
            u.s.Al[mn][kk] = (unsigned short)(pa[i] >> 16);
            u.s.Bh[mn][kk] = (unsigned short)pb[i];
            u.s.Bl[mn][kk] = (unsigned short)(pb[i] >> 16);
        }
    };

    loadA(0); loadB(0);
    commit();
    __syncthreads();

    for (int t = 0; t < KH / 32; ++t) {
        const bool more = (t + 1 < KH / 32);
        if (more) { loadA(t + 1); loadB(t + 1); }

        const int fr = lane & 15;
        const int kq = (lane >> 4) * 8;
        bf16x8 ah[2], al[2], bh[2], bl[2];
        #pragma unroll
        for (int f = 0; f < 2; ++f) {
            ah[f] = *(const bf16x8*)&u.s.Ah[wm + f * 16 + fr][kq];
            al[f] = *(const bf16x8*)&u.s.Al[wm + f * 16 + fr][kq];
            bh[f] = *(const bf16x8*)&u.s.Bh[wn + f * 16 + fr][kq];
            bl[f] = *(const bf16x8*)&u.s.Bl[wn + f * 16 + fr][kq];
        }
        #pragma unroll
        for (int fm = 0; fm < 2; ++fm)
            #pragma unroll
            for (int fn = 0; fn < 2; ++fn) {
                acc[fm][fn] = __builtin_amdgcn_mfma_f32_16x16x32_bf16(ah[fm], bh[fn], acc[fm][fn], 0, 0, 0);
                acc[fm][fn] = __builtin_amdgcn_mfma_f32_16x16x32_bf16(ah[fm], bl[fn], acc[fm][fn], 0, 0, 0);
                acc[fm][fn] = __builtin_amdgcn_mfma_f32_16x16x32_bf16(al[fm], bh[fn], acc[fm][fn], 0, 0, 0);
            }
        __syncthreads();
        if (more) {
            commit();
            __syncthreads();
        }
    }

    // --- spill z-tile to LDS (union member switch: all prior reads synced) ---
    {
        const int rm = (lane >> 4) * 4;
        const int cn = lane & 15;
        #pragma unroll
        for (int fm = 0; fm < 2; ++fm)
            #pragma unroll
            for (int fn = 0; fn < 2; ++fn) {
                int m = wm + fm * 16 + rm;
                int n = wn + fn * 16 + cn;
                *(float4*)&u.zt[n][m] = *(float4*)&acc[fm][fn];
            }
    }
    __syncthreads();

    // --- gate math: 1024 cell elements (64 m x 16 hid), 4 per thread ---
    #pragma unroll
    for (int i = 0; i < 4; ++i) {
        int e = i * 256 + tid;
        int m = e & 63;
        int j = e >> 6;             // hid slice index 0..15
        float g[4];
        #pragma unroll
        for (int gi = 0; gi < 4; ++gi) {
            int n_orig = gi * 128 + hid0 + j;
            g[gi] = u.zt[gi * 16 + j][m]
                  + zx_s[((long)b * COUT + n_orig) * HW + hw0 + m]
                  + bias[n_orig];
        }
        long idx_s = ((long)(b * HID + hid0 + j)) * HW + hw0 + m;
        float si = 1.f / (1.f + expf(-g[0]));
        float sf = 1.f / (1.f + expf(-g[1]));
        float so = 1.f / (1.f + expf(-g[3]));
        float cs = sf * c[idx_s] + si * tanhf(g[2]);
        float hs = so * tanhf(cs);
        c[idx_s] = cs;
        hout[idx_s] = packhl(hs);
    }
}

// ---------------------------------------------------------------------------
// Mean pool over HW: seq_hl [S][B][HID][HW] packed -> pooled [S*B*HID]
// ---------------------------------------------------------------------------
__global__ void pool_kernel(const unsigned* __restrict__ seq_hl, float* __restrict__ pooled) {
    int row  = blockIdx.x * 4 + (threadIdx.x >> 6);
    int lane = threadIdx.x & 63;
    const unsigned* p = seq_hl + (long)row * HW;
    float sum = 0.f;
    #pragma unroll
    for (int i = 0; i < HW / 64; ++i) {
        unsigned u = p[lane + i * 64];
        sum += bf2f((unsigned short)u) + bf2f((unsigned short)(u >> 16));
    }
    #pragma unroll
    for (int off = 32; off; off >>= 1) sum += __shfl_down(sum, off);
    if (lane == 0) pooled[row] = sum * (1.f / HW);
}

// ---------------------------------------------------------------------------
// FC + ReLU + two scalar heads.
// ---------------------------------------------------------------------------
__global__ void head_kernel(const float* __restrict__ pooled,
                            const float* __restrict__ fc_w, const float* __restrict__ fc_b,
                            const float* __restrict__ fco_w, const float* __restrict__ fco_b,
                            const float* __restrict__ fca_w, const float* __restrict__ fca_b,
                            float* __restrict__ out) {
    int bs = blockIdx.x;          // b*S + s
    int b  = bs / SS;
    int s  = bs % SS;
    int j  = threadIdx.x;
    const float* prow = pooled + (long)(s * BB + b) * HID;
    float acc = fc_b[j];
    #pragma unroll 4
    for (int k = 0; k < HID; ++k) acc += fc_w[j * HID + k] * prow[k];
    float f = fmaxf(acc, 0.f);
    __shared__ float ro[128], ra[128];
    ro[j] = f * fco_w[j];
    ra[j] = f * fca_w[j];
    __syncthreads();
    for (int off = 64; off; off >>= 1) {
        if (j < off) { ro[j] += ro[j + off]; ra[j] += ra[j + off]; }
        __syncthreads();
    }
    if (j == 0) {
        out[bs]           = ro[0] + fco_b[0];
        out[BB * SS + bs] = ra[0] + fca_b[0];
    }
}

// ---------------------------------------------------------------------------
extern "C" void kernel_launch(void* const* d_in, const int* in_sizes, int n_in,
                              void* d_out, int out_size, void* d_ws, size_t ws_size,
                              hipStream_t stream) {
    const float* x      = (const float*)d_in[0];
    const float* conv_w = (const float*)d_in[1];
    const float* conv_b = (const float*)d_in[2];
    const float* init_h = (const float*)d_in[3];
    const float* init_c = (const float*)d_in[4];
    const float* fc_w   = (const float*)d_in[5];
    const float* fc_b   = (const float*)d_in[6];
    const float* fco_w  = (const float*)d_in[7];
    const float* fco_b  = (const float*)d_in[8];
    const float* fca_w  = (const float*)d_in[9];
    const float* fca_b  = (const float*)d_in[10];
    float* out = (float*)d_out;

    // Workspace carve-up (4B units), total ~44.8M words = ~179 MB.
    unsigned* wtx_hl = (unsigned*)d_ws;                    // DEPTH*KH*COUT = 1,179,648
    unsigned* wth_hl = wtx_hl + (long)DEPTH * KH * COUT;   // 1,179,648
    float* zx        = (float*)(wth_hl + (long)DEPTH * KH * COUT); // S*B*COUT*HW = 33,554,432
    unsigned* seq_hl = (unsigned*)(zx + (long)SS * BB * COUT * HW); // S*B*HID*HW = 8,388,608
    unsigned* hhl    = seq_hl + (long)SS * BB * HID * HW;           // 262,144
    float* cbuf      = (float*)(hhl + (long)BB * HID * HW);         // 262,144
    float* pooled    = cbuf + (long)BB * HID * HW;                  // 16,384

    transpose_w_kernel<<<(DEPTH * K9 * COUT + 255) / 256, 256, 0, stream>>>(conv_w, wtx_hl, wth_hl);

    const long ZSTEP = (long)BB * COUT * HW;
    const long QSTEP = (long)BB * HID * HW;

    for (int d = 0; d < DEPTH; ++d) {
        // x-part of the conv for ALL timesteps: one big parallel MFMA GEMM
        if (d == 0)
            big_gemm_mfma<0><<<dim3(MBIG / 128, COUT / 128), 256, 0, stream>>>(
                x, (long)CC * HW, (long)SS * CC * HW, wtx_hl, zx);
        else
            big_gemm_mfma<1><<<dim3(MBIG / 128, COUT / 128), 256, 0, stream>>>(
                seq_hl, (long)BB * HID * HW, (long)HID * HW, wtx_hl + (long)KH * COUT, zx);

        init_state_kernel<<<(BB * HID * HW) / 256, 256, 0, stream>>>(init_h, init_c, hhl, cbuf, d);

        const unsigned* wth_d = wth_hl + (long)d * KH * COUT;
        const float* bias_d   = conv_b + d * COUT;
        for (int s = 0; s < SS; ++s) {
            const unsigned* hin = (s == 0) ? hhl : seq_hl + (long)(s - 1) * QSTEP;
            step_fused<<<dim3(MM / 64, HID / 16), 256, 0, stream>>>(
                hin, wth_d, zx + (long)s * ZSTEP, bias_d, cbuf, seq_hl + (long)s * QSTEP);
        }
    }
    pool_kernel<<<(SS * BB * HID) / 4, 256, 0, stream>>>(seq_hl, pooled);
    head_kernel<<<BB * SS, 128, 0, stream>>>(pooled, fc_w, fc_b, fco_w, fco_b, fca_w, fca_b, out);
}

// Round 10
// 2303.293 us; speedup vs baseline: 1.5046x; 1.3006x over previous
//
#include <hip/hip_runtime.h>

// Problem constants
#define BB 4
#define SS 32
#define CC 128
#define HH 16
#define WW 32
#define HID 128
#define DEPTH 2
#define CIN 256           // CC + HID
#define COUT 512          // 4*HID
#define K9 (CIN * 9)      // 2304
#define KH 1152           // tap-major: k = tap*128 + ch
#define HW (HH * WW)      // 512
#define MM (BB * HW)      // 2048
#define MBIG (SS * BB * HW) // 65536

typedef __attribute__((ext_vector_type(4))) float f32x4;
typedef __attribute__((ext_vector_type(8))) short bf16x8;

static __device__ __forceinline__ unsigned short f2bf(float f) {
    union { float f; unsigned u; } v; v.f = f;
    unsigned r = v.u + 0x7FFF + ((v.u >> 16) & 1);   // RNE
    return (unsigned short)(r >> 16);
}
static __device__ __forceinline__ float bf2f(unsigned short h) {
    union { float f; unsigned u; } v; v.u = ((unsigned)h) << 16; return v.f;
}
static __device__ __forceinline__ unsigned packhl(float f) {
    unsigned short hi = f2bf(f);
    unsigned short lo = f2bf(f - bf2f(hi));
    return (unsigned)hi | ((unsigned)lo << 16);
}

// ---------------------------------------------------------------------------
// Weight split+transpose (tap-major k), packed bf16 hi|lo:
//   wtx_hl [DEPTH][KH][COUT]  x-part, n unchanged
//   wth_hl [DEPTH][KH][COUT]  h-part, n GATE-GATHERED: n' = hb*64 + g*16 + j
// ---------------------------------------------------------------------------
__global__ void transpose_w_kernel(const float* __restrict__ w,
                                   unsigned* __restrict__ wtx_hl,
                                   unsigned* __restrict__ wth_hl) {
    int idx = blockIdx.x * 256 + threadIdx.x;
    if (idx >= DEPTH * K9 * COUT) return;
    int n = idx % COUT;
    int k = (idx / COUT) % K9;
    int d = idx / (COUT * K9);
    int cin = k / 9, tap = k % 9;
    float v = w[(((long)(d * COUT + n) * CIN + cin) * 9) + tap];
    unsigned p = packhl(v);
    if (cin < CC) {
        wtx_hl[((long)d * KH + (tap * CC + cin)) * COUT + n] = p;
    } else {
        int ch = cin - CC;
        int g = n >> 7, r = n & 127;
        int ng = (r >> 4) * 64 + g * 16 + (r & 15);
        wth_hl[((long)d * KH + (tap * HID + ch)) * COUT + ng] = p;
    }
}

// ---------------------------------------------------------------------------
// Broadcast init_h/init_c[d] into packed-h / fp32-c state buffers
// ---------------------------------------------------------------------------
__global__ void init_state_kernel(const float* __restrict__ ih, const float* __restrict__ ic,
                                  unsigned* __restrict__ hhl, float* __restrict__ c, int d) {
    int idx = blockIdx.x * 256 + threadIdx.x;   // B*HID*HW = 262144
    int hid = (idx >> 9) & (HID - 1);
    hhl[idx] = packhl(ih[d * HID + hid]);
    c[idx] = ic[d * HID + hid];
}

// ---------------------------------------------------------------------------
// Big feed-forward GEMM over ALL timesteps — MFMA bf16x3 (hi/lo split).
// Tile 128x128, 4 waves (2x2 of 64x64), BK=64, register-prefetch double
// buffering, paired b32 LDS commits. grid = (512, 4).
// ---------------------------------------------------------------------------
template<int HL>
__launch_bounds__(256)
__global__ void big_gemm_mfma(const void* __restrict__ xin_, long strideS, long strideB,
                              const unsigned* __restrict__ wt_hl,  // [KH][COUT]
                              float* __restrict__ zx) {
    __shared__ unsigned short Ah[2][128][36], Al[2][128][36];
    __shared__ unsigned short Bh[2][128][36], Bl[2][128][36];

    const int m0 = blockIdx.x * 128;
    const int n0 = blockIdx.y * 128;
    const int tid  = threadIdx.x;
    const int lane = tid & 63;
    const int wid  = tid >> 6;          // 4 waves
    const int wm = (wid >> 1) * 64;
    const int wn = (wid & 1) * 64;
    const int sb  = m0 >> 9;            // image index
    const int hw0 = m0 & 511;
    const long imgoff = (long)(sb >> 2) * strideS + (long)(sb & 3) * strideB;
    const float*    imgf = (const float*)xin_ + imgoff;
    const unsigned* imgu = (const unsigned*)xin_ + imgoff;

    f32x4 acc[4][4];
    #pragma unroll
    for (int i = 0; i < 4; ++i)
        #pragma unroll
        for (int j = 0; j < 4; ++j)
            acc[i][j] = (f32x4){0.f, 0.f, 0.f, 0.f};

    unsigned pa[32], pb[32];            // prefetch: 16 channel-pairs each

    auto loadA = [&](int t) {
        const int k0  = t * 64;
        const int tap = k0 >> 7;
        const int c0  = k0 & 127;
        const int ky  = tap / 3 - 1;
        const int kx  = tap - (tap / 3) * 3 - 1;
        #pragma unroll
        for (int i = 0; i < 16; ++i) {
            int idx = i * 256 + tid;    // 0..4095 : kkp = pair index, m
            int kkp = idx >> 7;         // 0..31
            int m   = idx & 127;
            int hw = hw0 + m;
            int yy = (hw >> 5) + ky;
            int xq = (hw & 31) + kx;
            bool ok = (unsigned)yy < (unsigned)HH && (unsigned)xq < (unsigned)WW;
            int ch = c0 + 2 * kkp;
            if constexpr (HL) {
                pa[2 * i]     = ok ? imgu[ch * HW + yy * WW + xq] : 0u;
                pa[2 * i + 1] = ok ? imgu[(ch + 1) * HW + yy * WW + xq] : 0u;
            } else {
                float v0 = ok ? imgf[ch * HW + yy * WW + xq] : 0.f;
                float v1 = ok ? imgf[(ch + 1) * HW + yy * WW + xq] : 0.f;
                pa[2 * i]     = packhl(v0);
                pa[2 * i + 1] = packhl(v1);
            }
        }
    };
    auto loadB = [&](int t) {
        const int k0 = t * 64;
        #pragma unroll
        for (int i = 0; i < 16; ++i) {
            int idx = i * 256 + tid;
            int kkp = idx >> 7;         // 0..31 (pair along k)
            int n   = idx & 127;
            pb[2 * i]     = wt_hl[(long)(k0 + 2 * kkp) * COUT + n0 + n];
            pb[2 * i + 1] = wt_hl[(long)(k0 + 2 * kkp + 1) * COUT + n0 + n];
        }
    };
    auto commit = [&]() {
        #pragma unroll
        for (int i = 0; i < 16; ++i) {
            int idx = i * 256 + tid;
            int kkp = idx >> 7;
            int mn  = idx & 127;
            int sub = kkp >> 4;
            int kl  = (2 * kkp) & 31;
            unsigned a0 = pa[2 * i], a1 = pa[2 * i + 1];
            *(unsigned*)&Ah[sub][mn][kl] = (a0 & 0xffffu) | (a1 << 16);
            *(unsigned*)&Al[sub][mn][kl] = (a0 >> 16) | (a1 & 0xffff0000u);
            unsigned b0 = pb[2 * i], b1 = pb[2 * i + 1];
            *(unsigned*)&Bh[sub][mn][kl] = (b0 & 0xffffu) | (b1 << 16);
            *(unsigned*)&Bl[sub][mn][kl] = (b0 >> 16) | (b1 & 0xffff0000u);
        }
    };

    loadA(0); loadB(0);
    commit();
    __syncthreads();

    const int fr = lane & 15;
    const int kq = (lane >> 4) * 8;

    for (int t = 0; t < KH / 64; ++t) {
        const bool more = (t + 1 < KH / 64);
        if (more) { loadA(t + 1); loadB(t + 1); }

        #pragma unroll
        for (int sub = 0; sub < 2; ++sub) {
            bf16x8 ah[4], al[4], bh[4], bl[4];
            #pragma unroll
            for (int f = 0; f < 4; ++f) {
                ah[f] = *(const bf16x8*)&Ah[sub][wm + f * 16 + fr][kq];
                al[f] = *(const bf16x8*)&Al[sub][wm + f * 16 + fr][kq];
                bh[f] = *(const bf16x8*)&Bh[sub][wn + f * 16 + fr][kq];
                bl[f] = *(const bf16x8*)&Bl[sub][wn + f * 16 + fr][kq];
            }
            #pragma unroll
            for (int fm = 0; fm < 4; ++fm)
                #pragma unroll
                for (int fn = 0; fn < 4; ++fn) {
                    acc[fm][fn] = __builtin_amdgcn_mfma_f32_16x16x32_bf16(ah[fm], bh[fn], acc[fm][fn], 0, 0, 0);
                    acc[fm][fn] = __builtin_amdgcn_mfma_f32_16x16x32_bf16(ah[fm], bl[fn], acc[fm][fn], 0, 0, 0);
                    acc[fm][fn] = __builtin_amdgcn_mfma_f32_16x16x32_bf16(al[fm], bh[fn], acc[fm][fn], 0, 0, 0);
                }
        }
        __syncthreads();
        if (more) {
            commit();
            __syncthreads();
        }
    }

    const long outbase = (long)sb * COUT * HW;
    const int rm = (lane >> 4) * 4;
    const int cn = lane & 15;
    #pragma unroll
    for (int fm = 0; fm < 4; ++fm)
        #pragma unroll
        for (int fn = 0; fn < 4; ++fn) {
            int m = hw0 + wm + fm * 16 + rm;
            int n = n0 + wn + fn * 16 + cn;
            *(float4*)&zx[outbase + (long)n * HW + m] = *(float4*)&acc[fm][fn];
        }
}

// ---------------------------------------------------------------------------
// FUSED per-step kernel: recurrent GEMM (full K=1152, MFMA bf16x3) + LSTM
// cell update epilogue. Restructured for TLP: m-tile 32 (one image row),
// BK=64, grid (64, 8) = 512 wgs -> 2 wg/CU; 4 waves (2m x 2n of 16x32).
// ---------------------------------------------------------------------------
__launch_bounds__(256)
__global__ void step_fused(const unsigned* __restrict__ hin,     // [B][HID][HW] packed h_{t-1}
                           const unsigned* __restrict__ wth_g,   // [KH][COUT] gate-gathered
                           const float* __restrict__ zx_s,       // [B][COUT][HW] step slice
                           const float* __restrict__ bias,       // [COUT] original order
                           float* __restrict__ c,                // [B][HID][HW] fp32 state
                           unsigned* __restrict__ hout) {        // [B][HID][HW] packed h_t
    __shared__ __align__(16) union {
        struct {
            unsigned short Ah[2][32][36], Al[2][32][36];   // 4.5 KB each pair
            unsigned short Bh[2][64][36], Bl[2][64][36];   // 9 KB each pair
        } s;                                               // 27 KB total
        float zt[64][36];   // [n_gathered][m] 9 KB
    } u;

    const int m0   = blockIdx.x * 32;       // one image row
    const int n0g  = blockIdx.y * 64;       // gathered-n base
    const int hid0 = blockIdx.y * 16;
    const int tid  = threadIdx.x;
    const int lane = tid & 63;
    const int wid  = tid >> 6;
    const int wm = (wid >> 1) * 16;         // m offset within 32
    const int wn = (wid & 1) * 32;          // n offset within 64
    const int b   = m0 >> 9;
    const int hw0 = m0 & 511;
    const int y0  = hw0 >> 5;               // image row

    f32x4 acc[2];
    acc[0] = (f32x4){0.f, 0.f, 0.f, 0.f};
    acc[1] = (f32x4){0.f, 0.f, 0.f, 0.f};

    unsigned pa[8], pb[16];
    auto loadA = [&](int t) {
        const int k0  = t * 64;
        const int tap = k0 >> 7;
        const int c0  = k0 & 127;           // 0 or 64
        const int ky  = tap / 3 - 1;
        const int kx  = tap - (tap / 3) * 3 - 1;
        const int yy  = y0 + ky;
        const bool yok = (unsigned)yy < (unsigned)HH;
        #pragma unroll
        for (int i = 0; i < 4; ++i) {
            int idx = i * 256 + tid;        // 0..1023
            int kkp = idx >> 5;             // ch pair 0..31
            int m   = idx & 31;
            int xq  = m + kx;
            bool ok = yok && (unsigned)xq < (unsigned)WW;
            int ch = c0 + 2 * kkp;
            long base = ((long)(b * HID + ch)) * HW + yy * WW + xq;
            pa[2 * i]     = ok ? hin[base] : 0u;
            pa[2 * i + 1] = ok ? hin[base + HW] : 0u;
        }
    };
    auto loadB = [&](int t) {
        const int k0 = t * 64;
        #pragma unroll
        for (int i = 0; i < 8; ++i) {
            int idx = i * 256 + tid;        // 0..2047
            int kkp = idx >> 6;             // k pair 0..31
            int n   = idx & 63;
            pb[2 * i]     = wth_g[(long)(k0 + 2 * kkp) * COUT + n0g + n];
            pb[2 * i + 1] = wth_g[(long)(k0 + 2 * kkp + 1) * COUT + n0g + n];
        }
    };
    auto commit = [&]() {
        #pragma unroll
        for (int i = 0; i < 4; ++i) {
            int idx = i * 256 + tid;
            int kkp = idx >> 5;
            int m   = idx & 31;
            int sub = kkp >> 4;
            int kl  = (2 * kkp) & 31;
            unsigned a0 = pa[2 * i], a1 = pa[2 * i + 1];
            *(unsigned*)&u.s.Ah[sub][m][kl] = (a0 & 0xffffu) | (a1 << 16);
            *(unsigned*)&u.s.Al[sub][m][kl] = (a0 >> 16) | (a1 & 0xffff0000u);
        }
        #pragma unroll
        for (int i = 0; i < 8; ++i) {
            int idx = i * 256 + tid;
            int kkp = idx >> 6;
            int n   = idx & 63;
            int sub = kkp >> 4;
            int kl  = (2 * kkp) & 31;
            unsigned b0 = pb[2 * i], b1 = pb[2 * i + 1];
            *(unsigned*)&u.s.Bh[sub][n][kl] = (b0 & 0xffffu) | (b1 << 16);
            *(unsigned*)&u.s.Bl[sub][n][kl] = (b0 >> 16) | (b1 & 0xffff0000u);
        }
    };

    loadA(0); loadB(0);
    commit();
    __syncthreads();

    const int fr = lane & 15;
    const int kq = (lane >> 4) * 8;

    for (int t = 0; t < KH / 64; ++t) {     // 18 iterations
        const bool more = (t + 1 < KH / 64);
        if (more) { loadA(t + 1); loadB(t + 1); }

        #pragma unroll
        for (int sub = 0; sub < 2; ++sub) {
            bf16x8 ah, al, bh[2], bl[2];
            ah = *(const bf16x8*)&u.s.Ah[sub][wm + fr][kq];
            al = *(const bf16x8*)&u.s.Al[sub][wm + fr][kq];
            #pragma unroll
            for (int f = 0; f < 2; ++f) {
                bh[f] = *(const bf16x8*)&u.s.Bh[sub][wn + f * 16 + fr][kq];
                bl[f] = *(const bf16x8*)&u.s.Bl[sub][wn + f * 16 + fr][kq];
            }
            #pragma unroll
            for (int fn = 0; fn < 2; ++fn) {
                acc[fn] = __builtin_amdgcn_mfma_f32_16x16x32_bf16(ah, bh[fn], acc[fn], 0, 0, 0);
                acc[fn] = __builtin_amdgcn_mfma_f32_16x16x32_bf16(ah, bl[fn], acc[fn], 0, 0, 0);
                acc[fn] = __builtin_amdgcn_mfma_f32_16x16x32_bf16(al, bh[fn], acc[fn], 0, 0, 0);
            }
        }
        __syncthreads();
        if (more) {
            commit();
            __syncthreads();
        }
    }

    // --- spill z-tile to LDS (union member switch: all prior reads synced) ---
    {
        const int rm = (lane >> 4) * 4;
        const int cn = lane & 15;
        #pragma unroll
        for (int fn = 0; fn < 2; ++fn) {
            int n = wn + fn * 16 + cn;
            *(float4*)&u.zt[n][wm + rm] = *(float4*)&acc[fn];
        }
    }
    __syncthreads();

    // --- gate math: 512 cell elements (32 m x 16 hid), 2 per thread ---
    #pragma unroll
    for (int i = 0; i < 2; ++i) {
        int e = i * 256 + tid;
        int m = e & 31;
        int j = e >> 5;             // hid slice index 0..15
        float g[4];
        #pragma unroll
        for (int gi = 0; gi < 4; ++gi) {
            int n_orig = gi * 128 + hid0 + j;
            g[gi] = u.zt[gi * 16 + j][m]
                  + zx_s[((long)b * COUT + n_orig) * HW + hw0 + m]
                  + bias[n_orig];
        }
        long idx_s = ((long)(b * HID + hid0 + j)) * HW + hw0 + m;
        float si = 1.f / (1.f + expf(-g[0]));
        float sf = 1.f / (1.f + expf(-g[1]));
        float so = 1.f / (1.f + expf(-g[3]));
        float cs = sf * c[idx_s] + si * tanhf(g[2]);
        float hs = so * tanhf(cs);
        c[idx_s] = cs;
        hout[idx_s] = packhl(hs);
    }
}

// ---------------------------------------------------------------------------
// Mean pool over HW: seq_hl [S][B][HID][HW] packed -> pooled [S*B*HID]
// ---------------------------------------------------------------------------
__global__ void pool_kernel(const unsigned* __restrict__ seq_hl, float* __restrict__ pooled) {
    int row  = blockIdx.x * 4 + (threadIdx.x >> 6);
    int lane = threadIdx.x & 63;
    const unsigned* p = seq_hl + (long)row * HW;
    float sum = 0.f;
    #pragma unroll
    for (int i = 0; i < HW / 64; ++i) {
        unsigned u = p[lane + i * 64];
        sum += bf2f((unsigned short)u) + bf2f((unsigned short)(u >> 16));
    }
    #pragma unroll
    for (int off = 32; off; off >>= 1) sum += __shfl_down(sum, off);
    if (lane == 0) pooled[row] = sum * (1.f / HW);
}

// ---------------------------------------------------------------------------
// FC + ReLU + two scalar heads.
// ---------------------------------------------------------------------------
__global__ void head_kernel(const float* __restrict__ pooled,
                            const float* __restrict__ fc_w, const float* __restrict__ fc_b,
                            const float* __restrict__ fco_w, const float* __restrict__ fco_b,
                            const float* __restrict__ fca_w, const float* __restrict__ fca_b,
                            float* __restrict__ out) {
    int bs = blockIdx.x;          // b*S + s
    int b  = bs / SS;
    int s  = bs % SS;
    int j  = threadIdx.x;
    const float* prow = pooled + (long)(s * BB + b) * HID;
    float acc = fc_b[j];
    #pragma unroll 4
    for (int k = 0; k < HID; ++k) acc += fc_w[j * HID + k] * prow[k];
    float f = fmaxf(acc, 0.f);
    __shared__ float ro[128], ra[128];
    ro[j] = f * fco_w[j];
    ra[j] = f * fca_w[j];
    __syncthreads();
    for (int off = 64; off; off >>= 1) {
        if (j < off) { ro[j] += ro[j + off]; ra[j] += ra[j + off]; }
        __syncthreads();
    }
    if (j == 0) {
        out[bs]           = ro[0] + fco_b[0];
        out[BB * SS + bs] = ra[0] + fca_b[0];
    }
}

// ---------------------------------------------------------------------------
extern "C" void kernel_launch(void* const* d_in, const int* in_sizes, int n_in,
                              void* d_out, int out_size, void* d_ws, size_t ws_size,
                              hipStream_t stream) {
    const float* x      = (const float*)d_in[0];
    const float* conv_w = (const float*)d_in[1];
    const float* conv_b = (const float*)d_in[2];
    const float* init_h = (const float*)d_in[3];
    const float* init_c = (const float*)d_in[4];
    const float* fc_w   = (const float*)d_in[5];
    const float* fc_b   = (const float*)d_in[6];
    const float* fco_w  = (const float*)d_in[7];
    const float* fco_b  = (const float*)d_in[8];
    const float* fca_w  = (const float*)d_in[9];
    const float* fca_b  = (const float*)d_in[10];
    float* out = (float*)d_out;

    // Workspace carve-up (4B units), total ~44.8M words = ~179 MB.
    unsigned* wtx_hl = (unsigned*)d_ws;                    // DEPTH*KH*COUT = 1,179,648
    unsigned* wth_hl = wtx_hl + (long)DEPTH * KH * COUT;   // 1,179,648
    float* zx        = (float*)(wth_hl + (long)DEPTH * KH * COUT); // S*B*COUT*HW = 33,554,432
    unsigned* seq_hl = (unsigned*)(zx + (long)SS * BB * COUT * HW); // S*B*HID*HW = 8,388,608
    unsigned* hhl    = seq_hl + (long)SS * BB * HID * HW;           // 262,144
    float* cbuf      = (float*)(hhl + (long)BB * HID * HW);         // 262,144
    float* pooled    = cbuf + (long)BB * HID * HW;                  // 16,384

    transpose_w_kernel<<<(DEPTH * K9 * COUT + 255) / 256, 256, 0, stream>>>(conv_w, wtx_hl, wth_hl);

    const long ZSTEP = (long)BB * COUT * HW;
    const long QSTEP = (long)BB * HID * HW;

    for (int d = 0; d < DEPTH; ++d) {
        // x-part of the conv for ALL timesteps: one big parallel MFMA GEMM
        if (d == 0)
            big_gemm_mfma<0><<<dim3(MBIG / 128, COUT / 128), 256, 0, stream>>>(
                x, (long)CC * HW, (long)SS * CC * HW, wtx_hl, zx);
        else
            big_gemm_mfma<1><<<dim3(MBIG / 128, COUT / 128), 256, 0, stream>>>(
                seq_hl, (long)BB * HID * HW, (long)HID * HW, wtx_hl + (long)KH * COUT, zx);

        init_state_kernel<<<(BB * HID * HW) / 256, 256, 0, stream>>>(init_h, init_c, hhl, cbuf, d);

        const unsigned* wth_d = wth_hl + (long)d * KH * COUT;
        const float* bias_d   = conv_b + d * COUT;
        for (int s = 0; s < SS; ++s) {
            const unsigned* hin = (s == 0) ? hhl : seq_hl + (long)(s - 1) * QSTEP;
            step_fused<<<dim3(MM / 32, HID / 16), 256, 0, stream>>>(
                hin, wth_d, zx + (long)s * ZSTEP, bias_d, cbuf, seq_hl + (long)s * QSTEP);
        }
    }
    pool_kernel<<<(SS * BB * HID) / 4, 256, 0, stream>>>(seq_hl, pooled);
    head_kernel<<<BB * SS, 128, 0, stream>>>(pooled, fc_w, fc_b, fco_w, fco_b, fca_w, fca_b, out);
}

// Round 11
// 2172.459 us; speedup vs baseline: 1.5952x; 1.0602x over previous
//
#include <hip/hip_runtime.h>

// Problem constants
#define BB 4
#define SS 32
#define CC 128
#define HH 16
#define WW 32
#define HID 128
#define DEPTH 2
#define CIN 256           // CC + HID
#define COUT 512          // 4*HID
#define K9 (CIN * 9)      // 2304
#define KH 1152           // per-source K: tap-major k = tap*128 + ch
#define KFULL (2 * KH)    // 2304 = x-part rows then h-part rows
#define HW (HH * WW)      // 512
#define MM (BB * HW)      // 2048
#define QS (BB * HID * HW)  // 262144, one step slice (also one packed-x slice)

typedef __attribute__((ext_vector_type(4))) float f32x4;
typedef __attribute__((ext_vector_type(8))) short bf16x8;

static __device__ __forceinline__ unsigned short f2bf(float f) {
    union { float f; unsigned u; } v; v.f = f;
    unsigned r = v.u + 0x7FFF + ((v.u >> 16) & 1);   // RNE
    return (unsigned short)(r >> 16);
}
static __device__ __forceinline__ float bf2f(unsigned short h) {
    union { float f; unsigned u; } v; v.u = ((unsigned)h) << 16; return v.f;
}
static __device__ __forceinline__ unsigned packhl(float f) {
    unsigned short hi = f2bf(f);
    unsigned short lo = f2bf(f - bf2f(hi));
    return (unsigned)hi | ((unsigned)lo << 16);
}

// ---------------------------------------------------------------------------
// Weight transpose: conv_w [DEPTH][COUT][CIN][3][3] -> wcat [DEPTH][KFULL][COUT]
// row: cin<CC -> tap*CC+cin (x block), else KH + tap*HID + (cin-CC) (h block).
// n GATE-GATHERED: n' = (r>>4)*64 + g*16 + (r&15), g=n>>7, r=n&127 — a 64-wide
// n-tile holds all 4 gates of one 16-hid slice. Packed bf16 hi|lo.
// ---------------------------------------------------------------------------
__global__ void transpose_w_kernel(const float* __restrict__ w,
                                   unsigned* __restrict__ wcat) {
    int idx = blockIdx.x * 256 + threadIdx.x;
    if (idx >= DEPTH * K9 * COUT) return;
    int n = idx % COUT;
    int k = (idx / COUT) % K9;
    int d = idx / (COUT * K9);
    int cin = k / 9, tap = k % 9;
    float v = w[(((long)(d * COUT + n) * CIN + cin) * 9) + tap];
    int row = (cin < CC) ? (tap * CC + cin) : (KH + tap * HID + (cin - CC));
    int g = n >> 7, r = n & 127;
    int ng = (r >> 4) * 64 + g * 16 + (r & 15);
    wcat[((long)d * KFULL + row) * COUT + ng] = packhl(v);
}

// ---------------------------------------------------------------------------
// Pack x [B][S][CC][HW] fp32 -> xpack [S][B][CC][HW] bf16 hi|lo u32
// ---------------------------------------------------------------------------
__global__ void pack_x_kernel(const float* __restrict__ x, unsigned* __restrict__ xp) {
    int idx = blockIdx.x * 256 + threadIdx.x;     // S*B*CC*HW = 8,388,608
    int hw = idx & 511;
    int cc = (idx >> 9) & 127;
    int sb = idx >> 16;          // s*BB + b
    int b  = sb & 3;
    int s  = sb >> 2;
    float v = x[(((long)(b * SS + s)) * CC + cc) * HW + hw];
    xp[idx] = packhl(v);
}

// ---------------------------------------------------------------------------
// Broadcast init_h/init_c[d] into packed-h / fp32-c state buffers
// ---------------------------------------------------------------------------
__global__ void init_state_kernel(const float* __restrict__ ih, const float* __restrict__ ic,
                                  unsigned* __restrict__ hhl, float* __restrict__ c, int d) {
    int idx = blockIdx.x * 256 + threadIdx.x;   // B*HID*HW = 262144
    int hid = (idx >> 9) & (HID - 1);
    hhl[idx] = packhl(ih[d * HID + hid]);
    c[idx] = ic[d * HID + hid];
}

// ---------------------------------------------------------------------------
// DUAL-LAYER fused step kernel. blockIdx.z selects layer; layer L runs its
// step's full conv GEMM (K=2304: 18 x-part tiles from xsrc, 18 h-part tiles
// from hsrc, tap-major, bf16x3 MFMA) + complete LSTM cell update.
// m-tile 32 (one image row), BK=64, 4 waves (2m x 2n of 16x32).
// grid = (64, 8, 2) = 1024 wgs -> ~4 wg/CU.
// ---------------------------------------------------------------------------
__launch_bounds__(256)
__global__ void step_dual(const unsigned* __restrict__ x1, const unsigned* __restrict__ h1,
                          float* __restrict__ c1, unsigned* __restrict__ ho1,
                          const unsigned* __restrict__ x2, const unsigned* __restrict__ h2,
                          float* __restrict__ c2, unsigned* __restrict__ ho2,
                          const unsigned* __restrict__ w1, const unsigned* __restrict__ w2,
                          const float* __restrict__ bias1, const float* __restrict__ bias2,
                          int do1, int do2) {
    __shared__ __align__(16) union {
        struct {
            unsigned short Ah[2][32][36], Al[2][32][36];   // 9.2 KB
            unsigned short Bh[2][64][36], Bl[2][64][36];   // 18.4 KB
        } s;                                               // 27.6 KB total
        float zt[64][36];   // [n_gathered][m] 9.2 KB
    } u;

    const int z = blockIdx.z;
    if (z == 0) { if (!do1) return; } else { if (!do2) return; }
    const unsigned* xsrc = z ? x2 : x1;
    const unsigned* hsrc = z ? h2 : h1;
    const unsigned* wsel = z ? w2 : w1;
    const float*    bsel = z ? bias2 : bias1;
    float*          csel = z ? c2 : c1;
    unsigned*       hosel = z ? ho2 : ho1;

    const int m0   = blockIdx.x * 32;       // one image row
    const int n0g  = blockIdx.y * 64;       // gathered-n base
    const int hid0 = blockIdx.y * 16;
    const int tid  = threadIdx.x;
    const int lane = tid & 63;
    const int wid  = tid >> 6;
    const int wm = (wid >> 1) * 16;         // m offset within 32
    const int wn = (wid & 1) * 32;          // n offset within 64
    const int b   = m0 >> 9;
    const int hw0 = m0 & 511;
    const int y0  = hw0 >> 5;               // image row

    f32x4 acc[2];
    acc[0] = (f32x4){0.f, 0.f, 0.f, 0.f};
    acc[1] = (f32x4){0.f, 0.f, 0.f, 0.f};

    unsigned pa[8], pb[16];
    auto loadA = [&](int tt) {
        const unsigned* asrc = (tt < 18) ? xsrc : hsrc;
        const int ksub = (tt < 18) ? tt : tt - 18;
        const int k0  = ksub * 64;
        const int tap = k0 >> 7;
        const int c0  = k0 & 127;           // 0 or 64
        const int ky  = tap / 3 - 1;
        const int kx  = tap - (tap / 3) * 3 - 1;
        const int yy  = y0 + ky;
        const bool yok = (unsigned)yy < (unsigned)HH;
        #pragma unroll
        for (int i = 0; i < 4; ++i) {
            int idx = i * 256 + tid;        // 0..1023
            int kkp = idx >> 5;             // ch pair 0..31
            int m   = idx & 31;
            int xq  = m + kx;
            bool ok = yok && (unsigned)xq < (unsigned)WW;
            int ch = c0 + 2 * kkp;
            long base = ((long)(b * 128 + ch)) * HW + yy * WW + xq;
            pa[2 * i]     = ok ? asrc[base] : 0u;
            pa[2 * i + 1] = ok ? asrc[base + HW] : 0u;
        }
    };
    auto loadB = [&](int tt) {
        const int k0 = tt * 64;             // row in wcat [KFULL]
        #pragma unroll
        for (int i = 0; i < 8; ++i) {
            int idx = i * 256 + tid;        // 0..2047
            int kkp = idx >> 6;             // k pair 0..31
            int n   = idx & 63;
            pb[2 * i]     = wsel[(long)(k0 + 2 * kkp) * COUT + n0g + n];
            pb[2 * i + 1] = wsel[(long)(k0 + 2 * kkp + 1) * COUT + n0g + n];
        }
    };
    auto commit = [&]() {
        #pragma unroll
        for (int i = 0; i < 4; ++i) {
            int idx = i * 256 + tid;
            int kkp = idx >> 5;
            int m   = idx & 31;
            int sub = kkp >> 4;
            int kl  = (2 * kkp) & 31;
            unsigned a0 = pa[2 * i], a1 = pa[2 * i + 1];
            *(unsigned*)&u.s.Ah[sub][m][kl] = (a0 & 0xffffu) | (a1 << 16);
            *(unsigned*)&u.s.Al[sub][m][kl] = (a0 >> 16) | (a1 & 0xffff0000u);
        }
        #pragma unroll
        for (int i = 0; i < 8; ++i) {
            int idx = i * 256 + tid;
            int kkp = idx >> 6;
            int n   = idx & 63;
            int sub = kkp >> 4;
            int kl  = (2 * kkp) & 31;
            unsigned b0 = pb[2 * i], b1 = pb[2 * i + 1];
            *(unsigned*)&u.s.Bh[sub][n][kl] = (b0 & 0xffffu) | (b1 << 16);
            *(unsigned*)&u.s.Bl[sub][n][kl] = (b0 >> 16) | (b1 & 0xffff0000u);
        }
    };

    loadA(0); loadB(0);
    commit();
    __syncthreads();

    const int fr = lane & 15;
    const int kq = (lane >> 4) * 8;

    for (int tt = 0; tt < 36; ++tt) {       // 36 tiles of 64 k
        const bool more = (tt + 1 < 36);
        if (more) { loadA(tt + 1); loadB(tt + 1); }

        #pragma unroll
        for (int sub = 0; sub < 2; ++sub) {
            bf16x8 ah, al, bh[2], bl[2];
            ah = *(const bf16x8*)&u.s.Ah[sub][wm + fr][kq];
            al = *(const bf16x8*)&u.s.Al[sub][wm + fr][kq];
            #pragma unroll
            for (int f = 0; f < 2; ++f) {
                bh[f] = *(const bf16x8*)&u.s.Bh[sub][wn + f * 16 + fr][kq];
                bl[f] = *(const bf16x8*)&u.s.Bl[sub][wn + f * 16 + fr][kq];
            }
            #pragma unroll
            for (int fn = 0; fn < 2; ++fn) {
                acc[fn] = __builtin_amdgcn_mfma_f32_16x16x32_bf16(ah, bh[fn], acc[fn], 0, 0, 0);
                acc[fn] = __builtin_amdgcn_mfma_f32_16x16x32_bf16(ah, bl[fn], acc[fn], 0, 0, 0);
                acc[fn] = __builtin_amdgcn_mfma_f32_16x16x32_bf16(al, bh[fn], acc[fn], 0, 0, 0);
            }
        }
        __syncthreads();
        if (more) {
            commit();
            __syncthreads();
        }
    }

    // --- spill z-tile to LDS (union member switch: all prior reads synced) ---
    {
        const int rm = (lane >> 4) * 4;
        const int cn = lane & 15;
        #pragma unroll
        for (int fn = 0; fn < 2; ++fn) {
            int n = wn + fn * 16 + cn;
            *(float4*)&u.zt[n][wm + rm] = *(float4*)&acc[fn];
        }
    }
    __syncthreads();

    // --- gate math: 512 cell elements (32 m x 16 hid), 2 per thread ---
    #pragma unroll
    for (int i = 0; i < 2; ++i) {
        int e = i * 256 + tid;
        int m = e & 31;
        int j = e >> 5;             // hid slice index 0..15
        float g[4];
        #pragma unroll
        for (int gi = 0; gi < 4; ++gi) {
            int n_orig = gi * 128 + hid0 + j;
            g[gi] = u.zt[gi * 16 + j][m] + bsel[n_orig];
        }
        long idx_s = ((long)(b * HID + hid0 + j)) * HW + hw0 + m;
        float si = 1.f / (1.f + expf(-g[0]));
        float sf = 1.f / (1.f + expf(-g[1]));
        float so = 1.f / (1.f + expf(-g[3]));
        float cs = sf * csel[idx_s] + si * tanhf(g[2]);
        float hs = so * tanhf(cs);
        csel[idx_s] = cs;
        hosel[idx_s] = packhl(hs);
    }
}

// ---------------------------------------------------------------------------
// Mean pool over HW: seq_hl [S][B][HID][HW] packed -> pooled [S*B*HID]
// ---------------------------------------------------------------------------
__global__ void pool_kernel(const unsigned* __restrict__ seq_hl, float* __restrict__ pooled) {
    int row  = blockIdx.x * 4 + (threadIdx.x >> 6);
    int lane = threadIdx.x & 63;
    const unsigned* p = seq_hl + (long)row * HW;
    float sum = 0.f;
    #pragma unroll
    for (int i = 0; i < HW / 64; ++i) {
        unsigned v = p[lane + i * 64];
        sum += bf2f((unsigned short)v) + bf2f((unsigned short)(v >> 16));
    }
    #pragma unroll
    for (int off = 32; off; off >>= 1) sum += __shfl_down(sum, off);
    if (lane == 0) pooled[row] = sum * (1.f / HW);
}

// ---------------------------------------------------------------------------
// FC + ReLU + two scalar heads.
// ---------------------------------------------------------------------------
__global__ void head_kernel(const float* __restrict__ pooled,
                            const float* __restrict__ fc_w, const float* __restrict__ fc_b,
                            const float* __restrict__ fco_w, const float* __restrict__ fco_b,
                            const float* __restrict__ fca_w, const float* __restrict__ fca_b,
                            float* __restrict__ out) {
    int bs = blockIdx.x;          // b*S + s
    int b  = bs / SS;
    int s  = bs % SS;
    int j  = threadIdx.x;
    const float* prow = pooled + (long)(s * BB + b) * HID;
    float acc = fc_b[j];
    #pragma unroll 4
    for (int k = 0; k < HID; ++k) acc += fc_w[j * HID + k] * prow[k];
    float f = fmaxf(acc, 0.f);
    __shared__ float ro[128], ra[128];
    ro[j] = f * fco_w[j];
    ra[j] = f * fca_w[j];
    __syncthreads();
    for (int off = 64; off; off >>= 1) {
        if (j < off) { ro[j] += ro[j + off]; ra[j] += ra[j + off]; }
        __syncthreads();
    }
    if (j == 0) {
        out[bs]           = ro[0] + fco_b[0];
        out[BB * SS + bs] = ra[0] + fca_b[0];
    }
}

// ---------------------------------------------------------------------------
extern "C" void kernel_launch(void* const* d_in, const int* in_sizes, int n_in,
                              void* d_out, int out_size, void* d_ws, size_t ws_size,
                              hipStream_t stream) {
    const float* x      = (const float*)d_in[0];
    const float* conv_w = (const float*)d_in[1];
    const float* conv_b = (const float*)d_in[2];
    const float* init_h = (const float*)d_in[3];
    const float* init_c = (const float*)d_in[4];
    const float* fc_w   = (const float*)d_in[5];
    const float* fc_b   = (const float*)d_in[6];
    const float* fco_w  = (const float*)d_in[7];
    const float* fco_b  = (const float*)d_in[8];
    const float* fca_w  = (const float*)d_in[9];
    const float* fca_b  = (const float*)d_in[10];
    float* out = (float*)d_out;

    // Workspace (4B units), total ~28.6M words = ~114 MB.
    unsigned* wcat  = (unsigned*)d_ws;                   // DEPTH*KFULL*COUT = 2,359,296
    unsigned* xpack = wcat + (long)DEPTH * KFULL * COUT; // S*B*CC*HW = 8,388,608
    unsigned* seq1  = xpack + (long)SS * QS;             // 8,388,608
    unsigned* seq2  = seq1 + (long)SS * QS;              // 8,388,608
    unsigned* hhl1  = seq2 + (long)SS * QS;              // 262,144
    float*    c1    = (float*)(hhl1 + QS);               // 262,144
    unsigned* hhl2  = (unsigned*)((float*)c1 + QS);      // 262,144
    float*    c2    = (float*)(hhl2 + QS);               // 262,144
    float*  pooled  = (float*)((float*)c2 + QS);         // 16,384

    transpose_w_kernel<<<(DEPTH * K9 * COUT + 255) / 256, 256, 0, stream>>>(conv_w, wcat);
    pack_x_kernel<<<(SS * QS) / 256, 256, 0, stream>>>(x, xpack);
    init_state_kernel<<<QS / 256, 256, 0, stream>>>(init_h, init_c, hhl1, c1, 0);
    init_state_kernel<<<QS / 256, 256, 0, stream>>>(init_h, init_c, hhl2, c2, 1);

    const unsigned* w1 = wcat;
    const unsigned* w2 = wcat + (long)KFULL * COUT;

    for (int t = 0; t <= SS; ++t) {
        int do1 = (t < SS) ? 1 : 0;
        int do2 = (t >= 1) ? 1 : 0;
        int t1 = (t < SS) ? t : SS - 1;          // clamped for safe ptr arith
        int u2 = (t >= 1) ? t - 1 : 0;
        const unsigned* x1 = xpack + (long)t1 * QS;
        const unsigned* h1 = (t1 == 0) ? hhl1 : seq1 + (long)(t1 - 1) * QS;
        unsigned* ho1 = seq1 + (long)t1 * QS;
        const unsigned* x2 = seq1 + (long)u2 * QS;
        const unsigned* h2 = (u2 == 0) ? hhl2 : seq2 + (long)(u2 - 1) * QS;
        unsigned* ho2 = seq2 + (long)u2 * QS;
        step_dual<<<dim3(MM / 32, HID / 16, 2), 256, 0, stream>>>(
            x1, h1, c1, ho1, x2, h2, c2, ho2,
            w1, w2, conv_b, conv_b + COUT, do1, do2);
    }

    pool_kernel<<<(SS * BB * HID) / 4, 256, 0, stream>>>(seq2, pooled);
    head_kernel<<<BB * SS, 128, 0, stream>>>(pooled, fc_w, fc_b, fco_w, fco_b, fca_w, fca_b, out);
}